// Round 1
// baseline (120.248 us; speedup 1.0000x reference)
//
#include <hip/hip_runtime.h>
#include <hip/hip_bf16.h>

#define SCALE_2LOG2E 2.8853900817779268f   // 2*log2(e): folded into projections
#define LOG2E 1.4426950408889634f

#define NB 8
#define TQ 32
#define TK 2048
#define DD 256

// ---------------------------------------------------------------------------
// K1: projection GEMM  C[m][u] = SCALE * sum_d A[m][d] * W[u][d]
// A: [M][256] row-major, W: [256][256] row-major (rows = u). 64x64 tile, BK=32.
// ---------------------------------------------------------------------------
__global__ __launch_bounds__(256) void proj_gemm(const float* __restrict__ A,
                                                 const float* __restrict__ W,
                                                 float* __restrict__ C) {
  __shared__ float As[32][68];
  __shared__ float Ws[32][68];
  const int tid = threadIdx.x;
  const int tm = tid >> 4, tn = tid & 15;
  const int m0 = blockIdx.x * 64, n0 = blockIdx.y * 64;
  float acc[4][4] = {};
  for (int k0 = 0; k0 < 256; k0 += 32) {
#pragma unroll
    for (int r = 0; r < 2; ++r) {
      int idx = tid + r * 256;          // 0..511: 64 rows x 8 float4
      int row = idx >> 3, c4 = idx & 7;
      float4 a = *(const float4*)(A + (m0 + row) * 256 + k0 + c4 * 4);
      float4 w = *(const float4*)(W + (n0 + row) * 256 + k0 + c4 * 4);
      As[c4 * 4 + 0][row] = a.x; As[c4 * 4 + 1][row] = a.y;
      As[c4 * 4 + 2][row] = a.z; As[c4 * 4 + 3][row] = a.w;
      Ws[c4 * 4 + 0][row] = w.x; Ws[c4 * 4 + 1][row] = w.y;
      Ws[c4 * 4 + 2][row] = w.z; Ws[c4 * 4 + 3][row] = w.w;
    }
    __syncthreads();
#pragma unroll
    for (int kk = 0; kk < 32; ++kk) {
      float4 a = *(const float4*)&As[kk][tm * 4];
      float4 w = *(const float4*)&Ws[kk][tn * 4];
      float av[4] = {a.x, a.y, a.z, a.w};
      float wv[4] = {w.x, w.y, w.z, w.w};
#pragma unroll
      for (int i = 0; i < 4; ++i)
#pragma unroll
        for (int j = 0; j < 4; ++j)
          acc[i][j] = fmaf(av[i], wv[j], acc[i][j]);
    }
    __syncthreads();
  }
#pragma unroll
  for (int i = 0; i < 4; ++i) {
    float4 o = make_float4(acc[i][0] * SCALE_2LOG2E, acc[i][1] * SCALE_2LOG2E,
                           acc[i][2] * SCALE_2LOG2E, acc[i][3] * SCALE_2LOG2E);
    *(float4*)(C + (m0 + tm * 4 + i) * 256 + n0 + tn * 4) = o;
  }
}

// ---------------------------------------------------------------------------
// K2: scores[b][q][k] = sum_u v[u]*tanh(qp+kp) = V0 - 2*sum_u v[u]/(exp2(qp'+kp')+1)
// grid (32 kchunks, 8 b), 512 threads (8 waves). Wave w: q in [4w,4w+4), lane = k.
// kp tile staged in 64KB LDS, float4-XOR-swizzled for bank-balanced b128 reads.
// qp / v rows are wave-uniform -> scalar loads.
// ---------------------------------------------------------------------------
__global__ __launch_bounds__(512) void score_kernel(const float* __restrict__ kproj,
                                                    const float* __restrict__ qproj,
                                                    const float* __restrict__ v,
                                                    float* __restrict__ scores) {
  __shared__ float kp[64 * 256];       // exactly 64 KB
  const int tid = threadIdx.x;
  const int b = blockIdx.y;
  const int kbase = blockIdx.x * 64;
#pragma unroll
  for (int i = 0; i < 8; ++i) {
    int idx4 = tid + i * 512;          // 0..4095 float4s
    int kk = idx4 >> 6, u4 = idx4 & 63;
    float4 t = *(const float4*)(kproj + (b * TK + kbase + kk) * 256 + u4 * 4);
    *(float4*)&kp[kk * 256 + ((u4 ^ (kk & 7)) << 2)] = t;
  }
  // V0 = sum(v), computed redundantly per wave
  const int lane = tid & 63;
  float vs = (v[lane] + v[lane + 64]) + (v[lane + 128] + v[lane + 192]);
#pragma unroll
  for (int off = 32; off; off >>= 1) vs += __shfl_xor(vs, off, 64);
  __syncthreads();

  const int wv = __builtin_amdgcn_readfirstlane(tid >> 6);  // wave id 0..7
  const int xorv = lane & 7;
  const float* qrow_base = qproj + (b * TQ + wv * 4) * 256;
  float* srow_base = scores + (b * TQ + wv * 4) * TK + kbase + lane;
#pragma unroll 1
  for (int qi = 0; qi < 4; ++qi) {
    const float* qrow = qrow_base + qi * 256;
    float sc = 0.f;
#pragma unroll 8
    for (int u4 = 0; u4 < 64; ++u4) {
      float4 kpv = *(const float4*)&kp[lane * 256 + ((u4 ^ xorv) << 2)];
      float4 qpv = *(const float4*)(qrow + u4 * 4);   // uniform -> s_load
      float4 vv = *(const float4*)(v + u4 * 4);       // uniform -> s_load
      float t0 = __builtin_amdgcn_exp2f(kpv.x + qpv.x);
      sc = fmaf(vv.x, __builtin_amdgcn_rcpf(t0 + 1.f), sc);
      float t1 = __builtin_amdgcn_exp2f(kpv.y + qpv.y);
      sc = fmaf(vv.y, __builtin_amdgcn_rcpf(t1 + 1.f), sc);
      float t2 = __builtin_amdgcn_exp2f(kpv.z + qpv.z);
      sc = fmaf(vv.z, __builtin_amdgcn_rcpf(t2 + 1.f), sc);
      float t3 = __builtin_amdgcn_exp2f(kpv.w + qpv.w);
      sc = fmaf(vv.w, __builtin_amdgcn_rcpf(t3 + 1.f), sc);
    }
    srow_base[qi * TK] = fmaf(-2.f, sc, vs);
  }
}

// ---------------------------------------------------------------------------
// K3: row softmax over 2048. One block per (b,q) row, 256 threads x 8 elems.
// ---------------------------------------------------------------------------
__global__ __launch_bounds__(256) void softmax_kernel(const float* __restrict__ scores,
                                                      float* __restrict__ attn) {
  const int row = blockIdx.x;
  const int tid = threadIdx.x;
  const float4* s4 = (const float4*)(scores + row * TK);
  float4 x0 = s4[tid], x1 = s4[tid + 256];
  float m = fmaxf(fmaxf(fmaxf(x0.x, x0.y), fmaxf(x0.z, x0.w)),
                  fmaxf(fmaxf(x1.x, x1.y), fmaxf(x1.z, x1.w)));
#pragma unroll
  for (int off = 32; off; off >>= 1) m = fmaxf(m, __shfl_xor(m, off, 64));
  __shared__ float redm[4], reds[4];
  const int lane = tid & 63, wv = tid >> 6;
  if (lane == 0) redm[wv] = m;
  __syncthreads();
  m = fmaxf(fmaxf(redm[0], redm[1]), fmaxf(redm[2], redm[3]));
  float e0 = __builtin_amdgcn_exp2f((x0.x - m) * LOG2E);
  float e1 = __builtin_amdgcn_exp2f((x0.y - m) * LOG2E);
  float e2 = __builtin_amdgcn_exp2f((x0.z - m) * LOG2E);
  float e3 = __builtin_amdgcn_exp2f((x0.w - m) * LOG2E);
  float e4 = __builtin_amdgcn_exp2f((x1.x - m) * LOG2E);
  float e5 = __builtin_amdgcn_exp2f((x1.y - m) * LOG2E);
  float e6 = __builtin_amdgcn_exp2f((x1.z - m) * LOG2E);
  float e7 = __builtin_amdgcn_exp2f((x1.w - m) * LOG2E);
  float s = ((e0 + e1) + (e2 + e3)) + ((e4 + e5) + (e6 + e7));
#pragma unroll
  for (int off = 32; off; off >>= 1) s += __shfl_xor(s, off, 64);
  if (lane == 0) reds[wv] = s;
  __syncthreads();
  float total = (reds[0] + reds[1]) + (reds[2] + reds[3]);
  float inv = __builtin_amdgcn_rcpf(total);
  float4* o4 = (float4*)(attn + row * TK);
  o4[tid] = make_float4(e0 * inv, e1 * inv, e2 * inv, e3 * inv);
  o4[tid + 256] = make_float4(e4 * inv, e5 * inv, e6 * inv, e7 * inv);
}

// ---------------------------------------------------------------------------
// K4: context partials: part[b][kc][q][d] = sum_{k in chunk} attn[b][q][k]*keys[b][k][d]
// grid (32 kchunks, 8 b), 256 threads (thread = d). keys chunk held in 64 VGPRs;
// attn via uniform scalar loads -> pure-FMA inner loop.
// ---------------------------------------------------------------------------
__global__ __launch_bounds__(256) void ctx_partial(const float* __restrict__ keys,
                                                   const float* __restrict__ attn,
                                                   float* __restrict__ part) {
  const int b = blockIdx.y, kc = blockIdx.x;
  const int d = threadIdx.x;
  const int kbase = kc * 64;
  float kv[64];
#pragma unroll
  for (int k = 0; k < 64; ++k)
    kv[k] = keys[(b * TK + kbase + k) * 256 + d];
  float* pout = part + (b * 32 + kc) * 8192 + d;
#pragma unroll 1
  for (int q = 0; q < 32; ++q) {
    const float4* ar = (const float4*)(attn + (b * TQ + q) * TK + kbase);  // uniform
    float a0 = 0.f, a1 = 0.f, a2 = 0.f, a3 = 0.f;
#pragma unroll
    for (int k4 = 0; k4 < 16; ++k4) {
      float4 av = ar[k4];
      a0 = fmaf(av.x, kv[k4 * 4 + 0], a0);
      a1 = fmaf(av.y, kv[k4 * 4 + 1], a1);
      a2 = fmaf(av.z, kv[k4 * 4 + 2], a2);
      a3 = fmaf(av.w, kv[k4 * 4 + 3], a3);
    }
    pout[q * 256] = (a0 + a1) + (a2 + a3);
  }
}

// ---------------------------------------------------------------------------
// K5: reduce partials over 32 kchunks -> context
// ---------------------------------------------------------------------------
__global__ __launch_bounds__(256) void ctx_reduce(const float* __restrict__ part,
                                                  float* __restrict__ ctx) {
  const int o = blockIdx.x * 256 + threadIdx.x;  // 0..65535  [b][q][d]
  const int b = o >> 13, qd = o & 8191;
  const float* p = part + b * 32 * 8192 + qd;
  float a0 = 0.f, a1 = 0.f, a2 = 0.f, a3 = 0.f;
#pragma unroll
  for (int kc = 0; kc < 8; ++kc) {
    a0 += p[(kc * 4 + 0) * 8192];
    a1 += p[(kc * 4 + 1) * 8192];
    a2 += p[(kc * 4 + 2) * 8192];
    a3 += p[(kc * 4 + 3) * 8192];
  }
  ctx[o] = (a0 + a1) + (a2 + a3);
}

extern "C" void kernel_launch(void* const* d_in, const int* in_sizes, int n_in,
                              void* d_out, int out_size, void* d_ws, size_t ws_size,
                              hipStream_t stream) {
  const float* query = (const float*)d_in[0];  // [8][32][256]
  const float* keys  = (const float*)d_in[1];  // [8][2048][256]
  const float* Wq    = (const float*)d_in[2];  // [256][256]
  const float* Wk    = (const float*)d_in[3];  // [256][256]
  const float* v     = (const float*)d_in[4];  // [256]

  float* out  = (float*)d_out;
  float* ctx  = out;           // 65536 floats: context [8][32][256]
  float* attn = out + 65536;   // 524288 floats: attn [8][32][2048]

  float* ws   = (float*)d_ws;
  float* kp   = ws;            // 16384*256 = 4194304
  float* qp   = ws + 4194304;  // 256*256   = 65536
  float* sc   = ws + 4259840;  // 256*2048  = 524288
  float* part = ws + 4784128;  // 256*8192  = 2097152  (total ~27.5 MB)

  proj_gemm<<<dim3(256, 4), 256, 0, stream>>>(keys, Wk, kp);
  proj_gemm<<<dim3(4, 4), 256, 0, stream>>>(query, Wq, qp);
  score_kernel<<<dim3(32, 8), 512, 0, stream>>>(kp, qp, v, sc);
  softmax_kernel<<<256, 256, 0, stream>>>(sc, attn);
  ctx_partial<<<dim3(32, 8), 256, 0, stream>>>(keys, attn, part);
  ctx_reduce<<<256, 256, 0, stream>>>(part, ctx);
}